// Round 3
// baseline (2522.987 us; speedup 1.0000x reference)
//
#include <hip/hip_runtime.h>

typedef unsigned int u32;

// SpMM: out[src[e], :] += att[e] * X[dst[e], :]
// edges int32 (2,E): src = edges[0..E), dst = edges[E..2E)
//
// Round-8: regroup-free accumulate via conflict-free LDS fp32 atomics.
//   prep1:        fused {per-chunk bucket histogram} + {X -> permuted bf16}
//   colscan_a:    per-(bucket, chunk-group) prefix over 49 chunks (4x par)
//   colscan_b:    1 block: per-bucket group bases + exclusive bucket scan
//   chunk_scatter: LDS cursors = bptr + gbase + hist; one pass; int2 records
//   accumulate:   per bucket (64 rows): zero 64x128 fp32 LDS tile, each
//                 32-lane group streams an unordered slice of the bucket's
//                 edges: gather permuted-bf16 row (256 B), a*x, 4x
//                 atomicAdd to LDS (ds_add_f32). Xb permuted so lane l holds
//                 feats {l,l+32,l+64,l+96} -> LDS addr row*128+l+32k = bank l
//                 (conflict-free). No row regroup, no ebuf, no CAP path,
//                 no accumulator dep chain. 512 thr x 32.8 KB -> 4 blk/CU
//                 -> 32 waves/CU occupancy ceiling (was ~50%).

constexpr int D_FEAT  = 128;
constexpr int N_NODES = 100000;
constexpr int BROWS   = 64;
constexpr int KB      = (N_NODES + BROWS - 1) / BROWS;   // 1563
constexpr int CHUNK   = 16384;
constexpr int NGRP    = 4;      // colscan chunk groups
constexpr int NCONV   = 120;    // extra blocks in prep1 doing X->bf16

__device__ __forceinline__ u32 rne_bf16(float f) {
    u32 u = __float_as_uint(f);
    return (u + 0x7FFFu + ((u >> 16) & 1u)) >> 16;
}

// ---------- 1: fused per-chunk histogram + X -> permuted bf16 ----------
// Xb[(node)*32 + l] = uint2 packing feats {l, l+32, l+64, l+96} of node.
__global__ __launch_bounds__(1024) void prep1(const int* __restrict__ src,
                                              u32* __restrict__ hist, int E, int nchunk,
                                              const float* __restrict__ X,
                                              uint2* __restrict__ Xb, int do_conv) {
    __shared__ u32 h[KB];
    const int blk = blockIdx.x;
    if (blk < nchunk) {
        const int e0 = blk * CHUNK;
        const int e1 = min(e0 + CHUNK, E);
        const int n  = e1 - e0;
        const int nfull = n & ~3;
        for (int i = threadIdx.x; i < KB; i += 1024) h[i] = 0;
        __syncthreads();
        for (int o = threadIdx.x * 4; o < nfull; o += 4096) {
            int4 s4 = *(const int4*)(src + e0 + o);
            atomicAdd(&h[s4.x >> 6], 1u);
            atomicAdd(&h[s4.y >> 6], 1u);
            atomicAdd(&h[s4.z >> 6], 1u);
            atomicAdd(&h[s4.w >> 6], 1u);
        }
        for (int o = nfull + threadIdx.x; o < n; o += 1024)
            atomicAdd(&h[src[e0 + o] >> 6], 1u);
        __syncthreads();
        u32* row = hist + (size_t)blk * KB;
        for (int i = threadIdx.x; i < KB; i += 1024) row[i] = h[i];
    } else if (do_conv) {
        const int nthreads = (gridDim.x - nchunk) * 1024;
        const int t0 = (blk - nchunk) * 1024 + threadIdx.x;
        for (int u = t0; u < N_NODES * 32; u += nthreads) {
            const int d = u >> 5, l = u & 31;
            const float* xr = X + (size_t)d * D_FEAT;
            uint2 o;
            o.x = rne_bf16(xr[l])      | (rne_bf16(xr[l + 32]) << 16);
            o.y = rne_bf16(xr[l + 64]) | (rne_bf16(xr[l + 96]) << 16);
            Xb[(size_t)d * 32 + l] = o;
        }
    }
}

// ---------- 2a: per-(bucket, group) prefix over its chunk range ----------
__global__ __launch_bounds__(256) void colscan_a(u32* __restrict__ hist,
                                                 u32* __restrict__ gt,
                                                 int nchunk, int gsz) {
    const int t = blockIdx.x * 256 + threadIdx.x;
    if (t >= KB * NGRP) return;
    const int g = t / KB;
    const int b = t - g * KB;
    const int c0 = g * gsz;
    const int c1 = min(c0 + gsz, nchunk);
    u32 run = 0;
    int c = c0;
    for (; c + 4 <= c1; c += 4) {
        u32 v0 = hist[(size_t)(c + 0) * KB + b];
        u32 v1 = hist[(size_t)(c + 1) * KB + b];
        u32 v2 = hist[(size_t)(c + 2) * KB + b];
        u32 v3 = hist[(size_t)(c + 3) * KB + b];
        hist[(size_t)(c + 0) * KB + b] = run;
        hist[(size_t)(c + 1) * KB + b] = run + v0;
        hist[(size_t)(c + 2) * KB + b] = run + v0 + v1;
        hist[(size_t)(c + 3) * KB + b] = run + v0 + v1 + v2;
        run += v0 + v1 + v2 + v3;
    }
    for (; c < c1; ++c) {
        u32 v = hist[(size_t)c * KB + b];
        hist[(size_t)c * KB + b] = run;
        run += v;
    }
    gt[(size_t)g * KB + b] = run;
}

// ---------- 2b (1 block): per-bucket group bases + exclusive bucket scan ----------
__global__ __launch_bounds__(1024) void colscan_b(const u32* __restrict__ gt,
                                                  u32* __restrict__ gbase,
                                                  u32* __restrict__ bptr) {
    __shared__ u32 s[1024];
    const int t = threadIdx.x;
    const int i0 = 2 * t, i1 = 2 * t + 1;
    u32 tot0 = 0, tot1 = 0;
    #pragma unroll
    for (int g = 0; g < NGRP; ++g) {
        if (i0 < KB) {
            u32 v = gt[(size_t)g * KB + i0];
            gbase[(size_t)g * KB + i0] = tot0;
            tot0 += v;
        }
        if (i1 < KB) {
            u32 v = gt[(size_t)g * KB + i1];
            gbase[(size_t)g * KB + i1] = tot1;
            tot1 += v;
        }
    }
    u32 tsum = tot0 + tot1;
    s[t] = tsum;
    __syncthreads();
    for (int o = 1; o < 1024; o <<= 1) {
        u32 v = (t >= o) ? s[t - o] : 0u;
        __syncthreads();
        s[t] += v;
        __syncthreads();
    }
    u32 excl = s[t] - tsum;
    if (i0 < KB) bptr[i0] = excl;
    if (i1 < KB) bptr[i1] = excl + tot0;
    if (t == 1023) bptr[KB] = s[1023];
}

// ---------- 3: scatter with precomputed LDS cursors ----------
__global__ __launch_bounds__(1024) void chunk_scatter(const int* __restrict__ src,
                                                      const int* __restrict__ dst,
                                                      const float* __restrict__ att,
                                                      const u32* __restrict__ bptr,
                                                      const u32* __restrict__ hist,
                                                      const u32* __restrict__ gbase,
                                                      int2* __restrict__ epack,
                                                      int E, int gsz) {
    __shared__ u32 cur[KB];
    const int c  = blockIdx.x;
    const int e0 = c * CHUNK;
    const int e1 = min(e0 + CHUNK, E);
    const int n  = e1 - e0;
    const int nfull = n & ~3;
    const u32* hrow = hist + (size_t)c * KB;
    const u32* grow = gbase + (size_t)(c / gsz) * KB;
    for (int i = threadIdx.x; i < KB; i += 1024)
        cur[i] = bptr[i] + grow[i] + hrow[i];
    __syncthreads();
    const bool v4ok = ((E & 3) == 0);   // dst = edges+E alignment for int4
    if (v4ok) {
        for (int o = threadIdx.x * 4; o < nfull; o += 4096) {
            int4   s4 = *(const int4*)(src + e0 + o);
            int4   d4 = *(const int4*)(dst + e0 + o);
            float4 a4 = *(const float4*)(att + e0 + o);
            #pragma unroll
            for (int k = 0; k < 4; ++k) {
                int s = (&s4.x)[k];
                u32 pos = atomicAdd(&cur[s >> 6], 1u);
                epack[pos] = make_int2(((s & 63) << 17) | (&d4.x)[k],
                                       __float_as_int((&a4.x)[k]));
            }
        }
        for (int o = nfull + threadIdx.x; o < n; o += 1024) {
            int s = src[e0 + o];
            u32 pos = atomicAdd(&cur[s >> 6], 1u);
            epack[pos] = make_int2(((s & 63) << 17) | dst[e0 + o],
                                   __float_as_int(att[e0 + o]));
        }
    } else {
        for (int o = threadIdx.x; o < n; o += 1024) {
            int s = src[e0 + o];
            u32 pos = atomicAdd(&cur[s >> 6], 1u);
            epack[pos] = make_int2(((s & 63) << 17) | dst[e0 + o],
                                   __float_as_int(att[e0 + o]));
        }
    }
}

// ---------- 4 (bf16): LDS-atomic accumulate, conflict-free banks ----------
__global__ __launch_bounds__(512, 8) void accumulate_atomic_bf16(
    const u32* __restrict__ bptr, const int2* __restrict__ epack,
    const uint2* __restrict__ Xb, float* __restrict__ out, int N)
{
    __shared__ float acc[BROWS * D_FEAT];   // 32 KB
    const int b   = blockIdx.x;
    const int tid = threadIdx.x;
    const int g   = tid >> 5;               // 16 groups of 32 lanes
    const int l   = tid & 31;
    const u32 s  = bptr[b];
    const u32 nb = bptr[b + 1] - s;
    const int row0 = b * BROWS;
    const int rows = min(BROWS, N - row0);

    // zero tile
    for (int i = tid; i < BROWS * 32; i += 512)
        ((float4*)acc)[i] = make_float4(0.f, 0.f, 0.f, 0.f);
    __syncthreads();

    // each group streams a contiguous slice of the bucket's edges
    const u32 j0 = s + (nb * (u32)g) / 16;
    const u32 j1 = s + (nb * (u32)(g + 1)) / 16;
    u32 j = j0;
    for (; j + 8 <= j1; j += 8) {
        int2 p[8]; uint2 q[8];
        #pragma unroll
        for (int k = 0; k < 8; ++k) p[k] = epack[j + k];
        #pragma unroll
        for (int k = 0; k < 8; ++k) q[k] = Xb[(size_t)(p[k].x & 0x1FFFF) * 32 + l];
        #pragma unroll
        for (int k = 0; k < 8; ++k) {
            const float a = __int_as_float(p[k].y);
            const u32 row = (u32)p[k].x >> 17;
            float* ap = &acc[(row << 7) + l];
            atomicAdd(ap +  0, a * __uint_as_float(q[k].x << 16));
            atomicAdd(ap + 32, a * __uint_as_float(q[k].x & 0xFFFF0000u));
            atomicAdd(ap + 64, a * __uint_as_float(q[k].y << 16));
            atomicAdd(ap + 96, a * __uint_as_float(q[k].y & 0xFFFF0000u));
        }
    }
    for (; j < j1; ++j) {
        const int2 p = epack[j];
        const uint2 q = Xb[(size_t)(p.x & 0x1FFFF) * 32 + l];
        const float a = __int_as_float(p.y);
        const u32 row = (u32)p.x >> 17;
        float* ap = &acc[(row << 7) + l];
        atomicAdd(ap +  0, a * __uint_as_float(q.x << 16));
        atomicAdd(ap + 32, a * __uint_as_float(q.x & 0xFFFF0000u));
        atomicAdd(ap + 64, a * __uint_as_float(q.y << 16));
        atomicAdd(ap + 96, a * __uint_as_float(q.y & 0xFFFF0000u));
    }
    __syncthreads();

    // coalesced store: thread -> (row, 4-feat chunk)
    for (int i = tid; i < rows * 32; i += 512) {
        const int r = i >> 5, l2 = i & 31;
        float4 v = *(const float4*)&acc[(r << 7) + (l2 << 2)];
        ((float4*)out)[(size_t)(row0 + r) * 32 + l2] = v;
    }
}

// ---------- 4 (fp32): fallback when ws can't hold Xb ----------
__global__ __launch_bounds__(512, 8) void accumulate_atomic_f32(
    const u32* __restrict__ bptr, const int2* __restrict__ epack,
    const float* __restrict__ X, float* __restrict__ out, int N)
{
    __shared__ float acc[BROWS * D_FEAT];
    const int b   = blockIdx.x;
    const int tid = threadIdx.x;
    const int g   = tid >> 5;
    const int l   = tid & 31;
    const u32 s  = bptr[b];
    const u32 nb = bptr[b + 1] - s;
    const int row0 = b * BROWS;
    const int rows = min(BROWS, N - row0);
    const float4* __restrict__ X4 = (const float4*)X;

    for (int i = tid; i < BROWS * 32; i += 512)
        ((float4*)acc)[i] = make_float4(0.f, 0.f, 0.f, 0.f);
    __syncthreads();

    const u32 j0 = s + (nb * (u32)g) / 16;
    const u32 j1 = s + (nb * (u32)(g + 1)) / 16;
    for (u32 j = j0; j < j1; ++j) {
        const int2 p = epack[j];
        const float4 v = X4[(size_t)(p.x & 0x1FFFF) * 32 + l];
        const float a = __int_as_float(p.y);
        const u32 row = (u32)p.x >> 17;
        float* ap = &acc[(row << 7) + (l << 2)];
        atomicAdd(ap + 0, a * v.x);
        atomicAdd(ap + 1, a * v.y);
        atomicAdd(ap + 2, a * v.z);
        atomicAdd(ap + 3, a * v.w);
    }
    __syncthreads();

    for (int i = tid; i < rows * 32; i += 512) {
        const int r = i >> 5, l2 = i & 31;
        float4 v = *(const float4*)&acc[(r << 7) + (l2 << 2)];
        ((float4*)out)[(size_t)(row0 + r) * 32 + l2] = v;
    }
}

// ---------- last-resort fallback: edge-parallel fp atomics ----------
__global__ __launch_bounds__(256) void spmm_edge_atomic(
    const int* __restrict__ src, const int* __restrict__ dst,
    const float* __restrict__ att, const float* __restrict__ X,
    float* __restrict__ out, int E)
{
    const int group = (int)((blockIdx.x * blockDim.x + threadIdx.x) >> 5);
    const int lane  = threadIdx.x & 31;
    const int nGroups = (int)((gridDim.x * blockDim.x) >> 5);
    for (int e = group; e < E; e += nGroups) {
        const int s = src[e], d = dst[e];
        const float a = att[e];
        const float4 v = ((const float4*)(X + (size_t)d * D_FEAT))[lane];
        float* o = out + (size_t)s * D_FEAT + (size_t)lane * 4;
        unsafeAtomicAdd(o + 0, a * v.x);
        unsafeAtomicAdd(o + 1, a * v.y);
        unsafeAtomicAdd(o + 2, a * v.z);
        unsafeAtomicAdd(o + 3, a * v.w);
    }
}

static inline size_t align16(size_t x) { return (x + 15) & ~(size_t)15; }

extern "C" void kernel_launch(void* const* d_in, const int* in_sizes, int n_in,
                              void* d_out, int out_size, void* d_ws, size_t ws_size,
                              hipStream_t stream) {
    const int*   edges = (const int*)d_in[0];   // (2, E) int32
    const float* att   = (const float*)d_in[1]; // (E,)
    const float* X     = (const float*)d_in[3]; // (N, 128)
    float*       out   = (float*)d_out;

    const int E = in_sizes[1];
    const int N = N_NODES;
    const int* src = edges;
    const int* dst = edges + E;
    const int nchunk = (E + CHUNK - 1) / CHUNK;
    const int gsz    = (nchunk + NGRP - 1) / NGRP;

    size_t o_hist  = 0;
    size_t o_gt    = o_hist  + (size_t)nchunk * KB * 4;
    size_t o_gbase = o_gt    + (size_t)NGRP * KB * 4;
    size_t o_bptr  = o_gbase + (size_t)NGRP * KB * 4;
    size_t o_epack = align16(o_bptr + ((size_t)KB + 1) * 4);
    size_t o_xb    = align16(o_epack + (size_t)E * 8);
    size_t need_f32  = o_xb;
    size_t need_bf16 = o_xb + (size_t)N * 32 * 8;   // uint2 per (node, lane)

    if (ws_size < need_f32) {
        hipMemsetAsync(d_out, 0, (size_t)out_size * sizeof(float), stream);
        const int grid = (E + 7) / 8;
        spmm_edge_atomic<<<grid, 256, 0, stream>>>(src, dst, att, X, out, E);
        return;
    }

    char* ws = (char*)d_ws;
    u32*  hist  = (u32*)(ws + o_hist);
    u32*  gt    = (u32*)(ws + o_gt);
    u32*  gbase = (u32*)(ws + o_gbase);
    u32*  bptr  = (u32*)(ws + o_bptr);
    int2* epack = (int2*)(ws + o_epack);
    uint2* Xb   = (uint2*)(ws + o_xb);

    const bool use_bf16 = (ws_size >= need_bf16);

    prep1<<<nchunk + (use_bf16 ? NCONV : 0), 1024, 0, stream>>>(
        src, hist, E, nchunk, X, Xb, use_bf16 ? 1 : 0);
    colscan_a<<<(KB * NGRP + 255) / 256, 256, 0, stream>>>(hist, gt, nchunk, gsz);
    colscan_b<<<1, 1024, 0, stream>>>(gt, gbase, bptr);
    chunk_scatter<<<nchunk, 1024, 0, stream>>>(src, dst, att, bptr, hist, gbase,
                                               epack, E, gsz);

    if (use_bf16)
        accumulate_atomic_bf16<<<KB, 512, 0, stream>>>(bptr, epack, Xb, out, N);
    else
        accumulate_atomic_f32<<<KB, 512, 0, stream>>>(bptr, epack, X, out, N);
}

// Round 4
// 354.398 us; speedup vs baseline: 7.1191x; 7.1191x over previous
//
#include <hip/hip_runtime.h>

typedef unsigned int u32;
typedef unsigned short u16;

// SpMM: out[src[e], :] += att[e] * X[dst[e], :]
// edges int32 (2,E): src = edges[0..E), dst = edges[E..2E)
//
// Round-9: proven regroup accumulate + occupancy-by-backfill + NT cache hints.
//   prep1:        fused {per-chunk(4096) bucket histogram (u16 matrix)} +
//                 {X -> bf16 pack}
//   colscan_a:    per-(bucket, chunk-group) prefix over ~98 chunks (8x par)
//   colscan_b:    1 block: per-bucket group bases + exclusive bucket scan
//   chunk_scatter: 782 blocks (3/CU, was 196 = latency-starved); LDS cursors
//                 = bptr + gbase + hist; int2 records, runs ~5 edges
//   accumulate:   128-row buckets, 1024 threads (16 waves): capacity 2
//                 blocks/CU = 32 waves; grid 782 = 3.05/CU -> backfill keeps
//                 occupancy high (rounds 0/2 were grid-resident-limited at
//                 ~50%: all blocks resident at t=0, no backfill, decay).
//                 Regroup 4B-packed ebuf (dst17|att_q15), 32 gather groups
//                 x 4 rows, unroll-8 bf16 gather, fp32 accumulate.
//                 NT loads on 2nd epack pass + NT out stores preserve L2
//                 for Xb gather lines.

constexpr int D_FEAT  = 128;
constexpr int N_NODES = 100000;
constexpr int BROWS   = 128;
constexpr int KB      = (N_NODES + BROWS - 1) / BROWS;   // 782
constexpr int CHUNK   = 4096;
constexpr int NGRP    = 8;      // colscan chunk groups
constexpr int NCONV   = 256;    // extra blocks in prep1 doing X->bf16
constexpr int CAP     = 4608;   // bucket mean 4092, sigma 64 -> +8 sigma

typedef float f32x4_v __attribute__((ext_vector_type(4)));
typedef int   i32x2_v __attribute__((ext_vector_type(2)));

__device__ __forceinline__ u32 rne_bf16(float f) {
    u32 u = __float_as_uint(f);
    return (u + 0x7FFFu + ((u >> 16) & 1u)) >> 16;
}

__device__ __forceinline__ void nt_store4(float* p, float x, float y, float z, float w) {
    f32x4_v t; t.x = x; t.y = y; t.z = z; t.w = w;
    __builtin_nontemporal_store(t, (f32x4_v*)p);
}

__device__ __forceinline__ int2 nt_load2(const int2* p) {
    i32x2_v t = __builtin_nontemporal_load((const i32x2_v*)p);
    return make_int2(t.x, t.y);
}

// ---------- 1: fused per-chunk histogram (u16) + X -> bf16 ----------
__global__ __launch_bounds__(512) void prep1(const int* __restrict__ src,
                                             u16* __restrict__ hist, int E, int nchunk,
                                             const float* __restrict__ X,
                                             uint2* __restrict__ Xb, int do_conv) {
    __shared__ u32 h[KB];
    const int blk = blockIdx.x;
    if (blk < nchunk) {
        const int e0 = blk * CHUNK;
        const int e1 = min(e0 + CHUNK, E);
        const int n  = e1 - e0;
        const int nfull = n & ~3;
        for (int i = threadIdx.x; i < KB; i += 512) h[i] = 0;
        __syncthreads();
        for (int o = threadIdx.x * 4; o < nfull; o += 2048) {
            int4 s4 = *(const int4*)(src + e0 + o);
            atomicAdd(&h[s4.x >> 7], 1u);
            atomicAdd(&h[s4.y >> 7], 1u);
            atomicAdd(&h[s4.z >> 7], 1u);
            atomicAdd(&h[s4.w >> 7], 1u);
        }
        for (int o = nfull + threadIdx.x; o < n; o += 512)
            atomicAdd(&h[src[e0 + o] >> 7], 1u);
        __syncthreads();
        u16* row = hist + (size_t)blk * KB;
        for (int i = threadIdx.x; i < KB; i += 512) row[i] = (u16)h[i];
    } else if (do_conv) {
        const int nthreads = (gridDim.x - nchunk) * 512;
        const float4* __restrict__ X4 = (const float4*)X;
        for (int u = (blk - nchunk) * 512 + threadIdx.x; u < N_NODES * 32;
             u += nthreads) {
            float4 v = X4[u];
            uint2 o;
            o.x = rne_bf16(v.x) | (rne_bf16(v.y) << 16);
            o.y = rne_bf16(v.z) | (rne_bf16(v.w) << 16);
            Xb[u] = o;
        }
    }
}

// ---------- 2a: per-(bucket, group) prefix over its chunk range ----------
__global__ __launch_bounds__(256) void colscan_a(u16* __restrict__ hist,
                                                 u32* __restrict__ gt,
                                                 int nchunk, int gsz) {
    const int t = blockIdx.x * 256 + threadIdx.x;
    if (t >= KB * NGRP) return;
    const int g = t / KB;
    const int b = t - g * KB;
    const int c0 = g * gsz;
    const int c1 = min(c0 + gsz, nchunk);
    u32 run = 0;
    int c = c0;
    for (; c + 4 <= c1; c += 4) {
        u32 v0 = hist[(size_t)(c + 0) * KB + b];
        u32 v1 = hist[(size_t)(c + 1) * KB + b];
        u32 v2 = hist[(size_t)(c + 2) * KB + b];
        u32 v3 = hist[(size_t)(c + 3) * KB + b];
        hist[(size_t)(c + 0) * KB + b] = (u16)run;
        hist[(size_t)(c + 1) * KB + b] = (u16)(run + v0);
        hist[(size_t)(c + 2) * KB + b] = (u16)(run + v0 + v1);
        hist[(size_t)(c + 3) * KB + b] = (u16)(run + v0 + v1 + v2);
        run += v0 + v1 + v2 + v3;
    }
    for (; c < c1; ++c) {
        u32 v = hist[(size_t)c * KB + b];
        hist[(size_t)c * KB + b] = (u16)run;
        run += v;
    }
    gt[(size_t)g * KB + b] = run;
}

// ---------- 2b (1 block): per-bucket group bases + exclusive bucket scan ----------
__global__ __launch_bounds__(1024) void colscan_b(const u32* __restrict__ gt,
                                                  u32* __restrict__ gbase,
                                                  u32* __restrict__ bptr) {
    __shared__ u32 s[1024];
    const int t = threadIdx.x;
    u32 tot = 0;
    if (t < KB) {
        #pragma unroll
        for (int g = 0; g < NGRP; ++g) {
            u32 v = gt[(size_t)g * KB + t];
            gbase[(size_t)g * KB + t] = tot;
            tot += v;
        }
    }
    s[t] = tot;
    __syncthreads();
    for (int o = 1; o < 1024; o <<= 1) {
        u32 v = (t >= o) ? s[t - o] : 0u;
        __syncthreads();
        s[t] += v;
        __syncthreads();
    }
    if (t < KB) bptr[t] = s[t] - tot;
    if (t == 1023) bptr[KB] = s[1023];
}

// ---------- 3: scatter with precomputed LDS cursors ----------
__global__ __launch_bounds__(512) void chunk_scatter(const int* __restrict__ src,
                                                     const int* __restrict__ dst,
                                                     const float* __restrict__ att,
                                                     const u32* __restrict__ bptr,
                                                     const u16* __restrict__ hist,
                                                     const u32* __restrict__ gbase,
                                                     int2* __restrict__ epack,
                                                     int E, int gsz) {
    __shared__ u32 cur[KB];
    const int c  = blockIdx.x;
    const int e0 = c * CHUNK;
    const int e1 = min(e0 + CHUNK, E);
    const int n  = e1 - e0;
    const int nfull = n & ~3;
    const u16* hrow = hist + (size_t)c * KB;
    const u32* grow = gbase + (size_t)(c / gsz) * KB;
    for (int i = threadIdx.x; i < KB; i += 512)
        cur[i] = bptr[i] + grow[i] + (u32)hrow[i];
    __syncthreads();
    const bool v4ok = ((E & 3) == 0);   // dst = edges+E alignment for int4
    if (v4ok) {
        for (int o = threadIdx.x * 4; o < nfull; o += 2048) {
            int4   s4 = *(const int4*)(src + e0 + o);
            int4   d4 = *(const int4*)(dst + e0 + o);
            float4 a4 = *(const float4*)(att + e0 + o);
            #pragma unroll
            for (int k = 0; k < 4; ++k) {
                int s = (&s4.x)[k];
                u32 pos = atomicAdd(&cur[s >> 7], 1u);
                epack[pos] = make_int2(((s & 127) << 17) | (&d4.x)[k],
                                       __float_as_int((&a4.x)[k]));
            }
        }
        for (int o = nfull + threadIdx.x; o < n; o += 512) {
            int s = src[e0 + o];
            u32 pos = atomicAdd(&cur[s >> 7], 1u);
            epack[pos] = make_int2(((s & 127) << 17) | dst[e0 + o],
                                   __float_as_int(att[e0 + o]));
        }
    } else {
        for (int o = threadIdx.x; o < n; o += 512) {
            int s = src[e0 + o];
            u32 pos = atomicAdd(&cur[s >> 7], 1u);
            epack[pos] = make_int2(((s & 127) << 17) | dst[e0 + o],
                                   __float_as_int(att[e0 + o]));
        }
    }
}

// ---------- shared LDS regroup: 128 rows, 4-byte packed ebuf, 1024 thr ----------
// pass 1 (hist) cached (re-hit by pass 2); pass 2 NT (last use).
#define REGROUP_BODY()                                                         \
    if (tid < BROWS) cnt[tid] = 0;                                             \
    __syncthreads();                                                           \
    for (int i = tid; i < nb; i += 1024)                                       \
        atomicAdd(&cnt[(u32)epack[s + i].x >> 17], 1u);                        \
    __syncthreads();                                                           \
    if (wave == 0) {                                                           \
        u32 c0 = cnt[2 * lane], c1 = cnt[2 * lane + 1];                        \
        u32 ps = c0 + c1;                                                      \
        u32 incl = ps;                                                         \
        _Pragma("unroll")                                                      \
        for (int o = 1; o < 64; o <<= 1) {                                     \
            u32 v = __shfl_up(incl, o, 64);                                    \
            if (lane >= o) incl += v;                                          \
        }                                                                      \
        u32 excl = incl - ps;                                                  \
        off[2 * lane]     = excl;      cur[2 * lane]     = excl;               \
        off[2 * lane + 1] = excl + c0; cur[2 * lane + 1] = excl + c0;          \
    }                                                                          \
    __syncthreads();                                                           \
    for (int i = tid; i < nb; i += 1024) {                                     \
        int2 p = nt_load2(epack + s + i);                                      \
        float af = __int_as_float(p.y);                                        \
        u32 q = (u32)(af * 32768.0f + 0.5f);                                   \
        q = min(q, 32767u);                                                    \
        u32 pos = atomicAdd(&cur[(u32)p.x >> 17], 1u);                         \
        ebuf[pos] = (((u32)p.x & 0x1FFFFu) << 15) | q;                         \
    }                                                                          \
    __syncthreads();

// ---------- 4 (bf16): per-bucket regroup + 32-lane bf16 gather ----------
__global__ __launch_bounds__(1024, 8) void accumulate_bucket_bf16(
    const u32* __restrict__ bptr, const int2* __restrict__ epack,
    const uint2* __restrict__ Xb, const float* __restrict__ X,
    float* __restrict__ out, int N)
{
    __shared__ u32 ebuf[CAP];
    __shared__ u32 cnt[BROWS], off[BROWS], cur[BROWS];
    const int b    = blockIdx.x;
    const int tid  = threadIdx.x;
    const int wave = tid >> 6;
    const int lane = tid & 63;
    const int g    = tid >> 5;               // 32 groups of 32 lanes
    const int l    = tid & 31;
    const u32 s = bptr[b], e = bptr[b + 1];
    const int nb = (int)(e - s);
    const int row0 = b * BROWS;
    const int rows = min(BROWS, N - row0);

    if (nb > CAP) {
        // Degenerate overflow path: zero rows, then fp32 edge atomics.
        float4* o4 = (float4*)(out + (size_t)row0 * D_FEAT);
        for (int i = tid; i < rows * 32; i += 1024) o4[i] = make_float4(0.f,0.f,0.f,0.f);
        __syncthreads();
        for (u32 k = s + g; k < e; k += 32) {
            int2 p = epack[k];
            int d = p.x & 0x1FFFF, sl = (u32)p.x >> 17;
            float a = __int_as_float(p.y);
            float4 v = ((const float4*)(X + (size_t)d * D_FEAT))[l];
            float* o = out + (size_t)(row0 + sl) * D_FEAT + l * 4;
            unsafeAtomicAdd(o + 0, a * v.x);
            unsafeAtomicAdd(o + 1, a * v.y);
            unsafeAtomicAdd(o + 2, a * v.z);
            unsafeAtomicAdd(o + 3, a * v.w);
        }
        return;
    }

    REGROUP_BODY()

    // one 32-lane group per row: uint2 = 4 bf16 per lane, unroll-8
    for (int r = g; r < rows; r += 32) {
        const u32 base = off[r];
        const u32 n    = cnt[r];
        float4 acc = make_float4(0.f, 0.f, 0.f, 0.f);
        u32 j = 0;
        for (; j + 8 <= n; j += 8) {
            u32 p[8]; uint2 q[8];
            #pragma unroll
            for (int k = 0; k < 8; ++k) p[k] = ebuf[base + j + k];
            #pragma unroll
            for (int k = 0; k < 8; ++k) q[k] = Xb[(size_t)(p[k] >> 15) * 32 + l];
            #pragma unroll
            for (int k = 0; k < 8; ++k) {
                const float a = (float)(p[k] & 0x7FFFu) * (1.0f / 32768.0f);
                acc.x = fmaf(a, __uint_as_float(q[k].x << 16),          acc.x);
                acc.y = fmaf(a, __uint_as_float(q[k].x & 0xFFFF0000u),  acc.y);
                acc.z = fmaf(a, __uint_as_float(q[k].y << 16),          acc.z);
                acc.w = fmaf(a, __uint_as_float(q[k].y & 0xFFFF0000u),  acc.w);
            }
        }
        for (; j + 2 <= n; j += 2) {
            const u32 p0 = ebuf[base + j];
            const u32 p1 = ebuf[base + j + 1];
            const uint2 q0 = Xb[(size_t)(p0 >> 15) * 32 + l];
            const uint2 q1 = Xb[(size_t)(p1 >> 15) * 32 + l];
            const float a0 = (float)(p0 & 0x7FFFu) * (1.0f / 32768.0f);
            const float a1 = (float)(p1 & 0x7FFFu) * (1.0f / 32768.0f);
            acc.x = fmaf(a0, __uint_as_float(q0.x << 16),         acc.x);
            acc.y = fmaf(a0, __uint_as_float(q0.x & 0xFFFF0000u), acc.y);
            acc.z = fmaf(a0, __uint_as_float(q0.y << 16),         acc.z);
            acc.w = fmaf(a0, __uint_as_float(q0.y & 0xFFFF0000u), acc.w);
            acc.x = fmaf(a1, __uint_as_float(q1.x << 16),         acc.x);
            acc.y = fmaf(a1, __uint_as_float(q1.x & 0xFFFF0000u), acc.y);
            acc.z = fmaf(a1, __uint_as_float(q1.y << 16),         acc.z);
            acc.w = fmaf(a1, __uint_as_float(q1.y & 0xFFFF0000u), acc.w);
        }
        if (j < n) {
            const u32 p = ebuf[base + j];
            const uint2 q = Xb[(size_t)(p >> 15) * 32 + l];
            const float a = (float)(p & 0x7FFFu) * (1.0f / 32768.0f);
            acc.x = fmaf(a, __uint_as_float(q.x << 16),         acc.x);
            acc.y = fmaf(a, __uint_as_float(q.x & 0xFFFF0000u), acc.y);
            acc.z = fmaf(a, __uint_as_float(q.y << 16),         acc.z);
            acc.w = fmaf(a, __uint_as_float(q.y & 0xFFFF0000u), acc.w);
        }
        nt_store4(out + (size_t)(row0 + r) * D_FEAT + l * 4,
                  acc.x, acc.y, acc.z, acc.w);
    }
}

// ---------- 4 (fp32): fallback when ws can't hold Xb ----------
__global__ __launch_bounds__(1024, 8) void accumulate_bucket_f32(
    const u32* __restrict__ bptr, const int2* __restrict__ epack,
    const float* __restrict__ X, float* __restrict__ out, int N)
{
    __shared__ u32 ebuf[CAP];
    __shared__ u32 cnt[BROWS], off[BROWS], cur[BROWS];
    const int b    = blockIdx.x;
    const int tid  = threadIdx.x;
    const int wave = tid >> 6;
    const int lane = tid & 63;
    const int g    = tid >> 5;
    const int l    = tid & 31;
    const u32 s = bptr[b], e = bptr[b + 1];
    const int nb = (int)(e - s);
    const int row0 = b * BROWS;
    const int rows = min(BROWS, N - row0);

    if (nb > CAP) {
        float4* o4 = (float4*)(out + (size_t)row0 * D_FEAT);
        for (int i = tid; i < rows * 32; i += 1024) o4[i] = make_float4(0.f,0.f,0.f,0.f);
        __syncthreads();
        for (u32 k = s + g; k < e; k += 32) {
            int2 p = epack[k];
            int d = p.x & 0x1FFFF, sl = (u32)p.x >> 17;
            float a = __int_as_float(p.y);
            float4 v = ((const float4*)(X + (size_t)d * D_FEAT))[l];
            float* o = out + (size_t)(row0 + sl) * D_FEAT + l * 4;
            unsafeAtomicAdd(o + 0, a * v.x);
            unsafeAtomicAdd(o + 1, a * v.y);
            unsafeAtomicAdd(o + 2, a * v.z);
            unsafeAtomicAdd(o + 3, a * v.w);
        }
        return;
    }

    REGROUP_BODY()

    const float4* __restrict__ X4 = (const float4*)X;
    for (int r = g; r < rows; r += 32) {
        const u32 base = off[r];
        const u32 n    = cnt[r];
        float4 acc = make_float4(0.f, 0.f, 0.f, 0.f);
        u32 j = 0;
        for (; j + 4 <= n; j += 4) {
            u32 p[4]; float4 v[4];
            #pragma unroll
            for (int k = 0; k < 4; ++k) p[k] = ebuf[base + j + k];
            #pragma unroll
            for (int k = 0; k < 4; ++k) v[k] = X4[(size_t)(p[k] >> 15) * 32 + l];
            #pragma unroll
            for (int k = 0; k < 4; ++k) {
                const float a = (float)(p[k] & 0x7FFFu) * (1.0f / 32768.0f);
                acc.x = fmaf(a, v[k].x, acc.x); acc.y = fmaf(a, v[k].y, acc.y);
                acc.z = fmaf(a, v[k].z, acc.z); acc.w = fmaf(a, v[k].w, acc.w);
            }
        }
        for (; j < n; ++j) {
            const u32 p = ebuf[base + j];
            const float4 v = X4[(size_t)(p >> 15) * 32 + l];
            const float a = (float)(p & 0x7FFFu) * (1.0f / 32768.0f);
            acc.x = fmaf(a, v.x, acc.x); acc.y = fmaf(a, v.y, acc.y);
            acc.z = fmaf(a, v.z, acc.z); acc.w = fmaf(a, v.w, acc.w);
        }
        nt_store4(out + (size_t)(row0 + r) * D_FEAT + l * 4,
                  acc.x, acc.y, acc.z, acc.w);
    }
}

// ---------- last-resort fallback: edge-parallel fp atomics ----------
__global__ __launch_bounds__(256) void spmm_edge_atomic(
    const int* __restrict__ src, const int* __restrict__ dst,
    const float* __restrict__ att, const float* __restrict__ X,
    float* __restrict__ out, int E)
{
    const int group = (int)((blockIdx.x * blockDim.x + threadIdx.x) >> 5);
    const int lane  = threadIdx.x & 31;
    const int nGroups = (int)((gridDim.x * blockDim.x) >> 5);
    for (int e = group; e < E; e += nGroups) {
        const int s = src[e], d = dst[e];
        const float a = att[e];
        const float4 v = ((const float4*)(X + (size_t)d * D_FEAT))[lane];
        float* o = out + (size_t)s * D_FEAT + (size_t)lane * 4;
        unsafeAtomicAdd(o + 0, a * v.x);
        unsafeAtomicAdd(o + 1, a * v.y);
        unsafeAtomicAdd(o + 2, a * v.z);
        unsafeAtomicAdd(o + 3, a * v.w);
    }
}

static inline size_t align16(size_t x) { return (x + 15) & ~(size_t)15; }

extern "C" void kernel_launch(void* const* d_in, const int* in_sizes, int n_in,
                              void* d_out, int out_size, void* d_ws, size_t ws_size,
                              hipStream_t stream) {
    const int*   edges = (const int*)d_in[0];   // (2, E) int32
    const float* att   = (const float*)d_in[1]; // (E,)
    const float* X     = (const float*)d_in[3]; // (N, 128)
    float*       out   = (float*)d_out;

    const int E = in_sizes[1];
    const int N = N_NODES;
    const int* src = edges;
    const int* dst = edges + E;
    const int nchunk = (E + CHUNK - 1) / CHUNK;
    const int gsz    = (nchunk + NGRP - 1) / NGRP;

    size_t o_hist  = 0;
    size_t o_gt    = align16(o_hist + (size_t)nchunk * KB * 2);   // u16 hist
    size_t o_gbase = o_gt    + (size_t)NGRP * KB * 4;
    size_t o_bptr  = o_gbase + (size_t)NGRP * KB * 4;
    size_t o_epack = align16(o_bptr + ((size_t)KB + 1) * 4);
    size_t o_xb    = align16(o_epack + (size_t)E * 8);
    size_t need_f32  = o_xb;
    size_t need_bf16 = o_xb + (size_t)N * D_FEAT * 2;

    if (ws_size < need_f32) {
        hipMemsetAsync(d_out, 0, (size_t)out_size * sizeof(float), stream);
        const int grid = (E + 7) / 8;
        spmm_edge_atomic<<<grid, 256, 0, stream>>>(src, dst, att, X, out, E);
        return;
    }

    char* ws = (char*)d_ws;
    u16*  hist  = (u16*)(ws + o_hist);
    u32*  gt    = (u32*)(ws + o_gt);
    u32*  gbase = (u32*)(ws + o_gbase);
    u32*  bptr  = (u32*)(ws + o_bptr);
    int2* epack = (int2*)(ws + o_epack);
    uint2* Xb   = (uint2*)(ws + o_xb);

    const bool use_bf16 = (ws_size >= need_bf16);

    prep1<<<nchunk + (use_bf16 ? NCONV : 0), 512, 0, stream>>>(
        src, hist, E, nchunk, X, Xb, use_bf16 ? 1 : 0);
    colscan_a<<<(KB * NGRP + 255) / 256, 256, 0, stream>>>(hist, gt, nchunk, gsz);
    colscan_b<<<1, 1024, 0, stream>>>(gt, gbase, bptr);
    chunk_scatter<<<nchunk, 512, 0, stream>>>(src, dst, att, bptr, hist, gbase,
                                              epack, E, gsz);

    if (use_bf16)
        accumulate_bucket_bf16<<<KB, 1024, 0, stream>>>(bptr, epack, Xb, X, out, N);
    else
        accumulate_bucket_f32<<<KB, 1024, 0, stream>>>(bptr, epack, X, out, N);
}